// Round 2
// baseline (456.803 us; speedup 1.0000x reference)
//
#include <hip/hip_runtime.h>
#include <hip/hip_bf16.h>

#define N_NODES 50000
#define N_EDGES 800000
#define DIM 128
#define NTILES (N_EDGES / 64)   // 12500 exactly

typedef __bf16 bf16x8 __attribute__((ext_vector_type(8)));
typedef float f32x4 __attribute__((ext_vector_type(4)));
typedef unsigned int u32x4 __attribute__((ext_vector_type(4)));

__device__ __forceinline__ unsigned short f2bf(float f) {
    unsigned u = __float_as_uint(f);
    u += 0x7fffu + ((u >> 16) & 1u);          // round-to-nearest-even
    return (unsigned short)(u >> 16);
}

// ---- convert W2 [256][128] -> W2t [128 n][256 k] bf16; W3 [128][128] -> W3t [128 n][128 k]
__global__ void convert_w_kernel(const float* __restrict__ W2, const float* __restrict__ W3,
                                 unsigned short* __restrict__ W2t, unsigned short* __restrict__ W3t) {
    int i = blockIdx.x * 256 + threadIdx.x;   // grid covers exactly 49152
    if (i < 2 * DIM * DIM) {
        int k = i >> 7, n = i & 127;
        W2t[n * 256 + k] = f2bf(W2[i]);
    } else {
        int j = i - 2 * DIM * DIM;
        int k = j >> 7, n = j & 127;
        W3t[n * 128 + k] = f2bf(W3[j]);
    }
}

// ---- counting sort of edges by dst: histogram
__global__ void hist_kernel(const int* __restrict__ eidx, int* __restrict__ cnt) {
    int e = blockIdx.x * 256 + threadIdx.x;
    if (e < N_EDGES) atomicAdd(&cnt[eidx[N_EDGES + e]], 1);
}

// ---- in-place exclusive scan of cnt[N_NODES] -> cursor (single block, 1024 thr)
__global__ __launch_bounds__(1024) void scan_kernel(int* __restrict__ cnt) {
    __shared__ int part[1024];
    int t = threadIdx.x;
    const int CH = 49;                        // 1024*49 = 50176 >= 50000
    int base = t * CH;
    int s = 0;
    for (int i = 0; i < CH; i++) {
        int idx = base + i;
        if (idx < N_NODES) s += cnt[idx];
    }
    part[t] = s;
    __syncthreads();
    for (int off = 1; off < 1024; off <<= 1) {
        int v = (t >= off) ? part[t - off] : 0;
        __syncthreads();
        part[t] += v;
        __syncthreads();
    }
    int run = (t == 0) ? 0 : part[t - 1];
    for (int i = 0; i < CH; i++) {
        int idx = base + i;
        if (idx < N_NODES) {
            int c = cnt[idx];
            cnt[idx] = run;                   // cnt becomes the scatter cursor
            run += c;
        }
    }
}

// ---- scatter edges into dst-sorted order
__global__ void scatter_kernel(const int* __restrict__ eidx, int* __restrict__ cursor,
                               int* __restrict__ ssrc, int* __restrict__ sdst) {
    int e = blockIdx.x * 256 + threadIdx.x;
    if (e < N_EDGES) {
        int d = eidx[N_EDGES + e];
        int p = atomicAdd(&cursor[d], 1);
        sdst[p] = d;
        ssrc[p] = eidx[e];
    }
}

// ---- lin1: hbf[N][128] = bf16(x @ W1 + b1), MFMA 16x16x32, W1 transposed in LDS
__global__ __launch_bounds__(256, 2) void lin1_kernel(const float* __restrict__ x,
        const float* __restrict__ W1, const float* __restrict__ b1,
        unsigned short* __restrict__ hbf) {
    __shared__ __align__(16) unsigned short w1t[128 * 136];   // [n][k] padded
    int tid = threadIdx.x;
    for (int i = tid; i < DIM * DIM; i += 256) {
        int k = i >> 7, n = i & 127;
        w1t[n * 136 + k] = f2bf(W1[i]);
    }
    __syncthreads();
    int w = tid >> 6, lane = tid & 63;
    int lr = lane & 15, q = lane >> 4;
    int row0 = blockIdx.x * 64 + w * 16;
    int rowA = row0 + lr; if (rowA >= N_NODES) rowA = N_NODES - 1;
    f32x4 acc[8];
    #pragma unroll
    for (int ct = 0; ct < 8; ct++) acc[ct] = (f32x4){0.f, 0.f, 0.f, 0.f};
    #pragma unroll
    for (int kt = 0; kt < 4; kt++) {
        const float* ap = x + (size_t)rowA * DIM + kt * 32 + q * 8;
        bf16x8 a;
        #pragma unroll
        for (int j = 0; j < 8; j++) a[j] = (__bf16)ap[j];
        #pragma unroll
        for (int ct = 0; ct < 8; ct++) {
            bf16x8 b = __builtin_bit_cast(bf16x8,
                *(const u32x4*)(&w1t[(ct * 16 + lr) * 136 + kt * 32 + q * 8]));
            acc[ct] = __builtin_amdgcn_mfma_f32_16x16x32_bf16(a, b, acc[ct], 0, 0, 0);
        }
    }
    #pragma unroll
    for (int ct = 0; ct < 8; ct++) {
        int col = ct * 16 + lr;
        float bias = b1[col];
        #pragma unroll
        for (int r = 0; r < 4; r++) {
            int row = row0 + q * 4 + r;   // C/D: col=lane&15, row=quad*4+reg
            if (row < N_NODES)
                hbf[(size_t)row * DIM + col] = f2bf(acc[ct][r] + bias);
        }
    }
}

// ---- fused edge MLP + segmented scatter-max over dst-sorted edges
__global__ __launch_bounds__(256, 2) void edge_kernel(
        const unsigned short* __restrict__ hbf,
        const int* __restrict__ ssrc,
        const int* __restrict__ sdst,
        const unsigned short* __restrict__ W2t,
        const unsigned short* __restrict__ W3t,
        const float* __restrict__ b2,
        const float* __restrict__ b3,
        unsigned int* __restrict__ out) {
    __shared__ __align__(16) unsigned short e_lds[64 * 264];    // [edge][256k]; reused as fp32 m2 [64][132]
    __shared__ __align__(16) unsigned short m1_lds[64 * 136];   // [edge][128k]
    __shared__ int s_src[64];
    __shared__ int s_dst[64];

    int tid = threadIdx.x;
    int w = tid >> 6, lane = tid & 63;
    int lr = lane & 15, q = lane >> 4;
    float* m2f = (float*)e_lds;                                 // [64][132] fp32

    // register-cached B fragments (fixed cols per wave, amortized over grid-stride loop)
    bf16x8 b2f[2][8], b3f[2][4];
    float b2v[2], b3v[2];
    #pragma unroll
    for (int ct = 0; ct < 2; ct++) {
        int n = (2 * w + ct) * 16 + lr;
        #pragma unroll
        for (int kt = 0; kt < 8; kt++)
            b2f[ct][kt] = __builtin_bit_cast(bf16x8, *(const u32x4*)(&W2t[n * 256 + kt * 32 + q * 8]));
        #pragma unroll
        for (int kt = 0; kt < 4; kt++)
            b3f[ct][kt] = __builtin_bit_cast(bf16x8, *(const u32x4*)(&W3t[n * 128 + kt * 32 + q * 8]));
        b2v[ct] = b2[n];
        b3v[ct] = b3[n];
    }

    for (int tb = blockIdx.x; tb < NTILES; tb += gridDim.x) {
        int eb = tb * 64;
        if (tid < 64) {
            s_src[tid] = ssrc[eb + tid];
            s_dst[tid] = sdst[eb + tid];
        }
        __syncthreads();

        // gather: e[t][0:128]=h_i(dst), e[t][128:256]=h_j(src)-h_i
        #pragma unroll
        for (int it = 0; it < 4; it++) {
            int i = tid + it * 256;
            int t = i >> 4, c = i & 15;
            u32x4 hi4 = *(const u32x4*)(&hbf[(size_t)s_dst[t] * DIM + c * 8]);
            u32x4 hj4 = *(const u32x4*)(&hbf[(size_t)s_src[t] * DIM + c * 8]);
            u32x4 df;
            #pragma unroll
            for (int jj = 0; jj < 4; jj++) {
                unsigned a = hi4[jj], b = hj4[jj];
                float dl = __uint_as_float(b << 16) - __uint_as_float(a << 16);
                float dh = __uint_as_float(b & 0xffff0000u) - __uint_as_float(a & 0xffff0000u);
                df[jj] = (unsigned)f2bf(dl) | ((unsigned)f2bf(dh) << 16);
            }
            *(u32x4*)(&e_lds[t * 264 + c * 8]) = hi4;
            *(u32x4*)(&e_lds[t * 264 + 128 + c * 8]) = df;
        }
        __syncthreads();

        // GEMM1: m1 = relu(e @ W2 + b2), K=256
        f32x4 acc1[4][2];
        #pragma unroll
        for (int rt = 0; rt < 4; rt++)
            #pragma unroll
            for (int ct = 0; ct < 2; ct++) acc1[rt][ct] = (f32x4){0.f, 0.f, 0.f, 0.f};
        #pragma unroll
        for (int kt = 0; kt < 8; kt++) {
            #pragma unroll
            for (int rt = 0; rt < 4; rt++) {
                bf16x8 a = __builtin_bit_cast(bf16x8,
                    *(const u32x4*)(&e_lds[(rt * 16 + lr) * 264 + kt * 32 + q * 8]));
                acc1[rt][0] = __builtin_amdgcn_mfma_f32_16x16x32_bf16(a, b2f[0][kt], acc1[rt][0], 0, 0, 0);
                acc1[rt][1] = __builtin_amdgcn_mfma_f32_16x16x32_bf16(a, b2f[1][kt], acc1[rt][1], 0, 0, 0);
            }
        }
        __syncthreads();   // all waves done reading e_lds (GEMM1) before m2f reuse
        #pragma unroll
        for (int rt = 0; rt < 4; rt++) {
            #pragma unroll
            for (int ct = 0; ct < 2; ct++) {
                int col = (2 * w + ct) * 16 + lr;
                #pragma unroll
                for (int r = 0; r < 4; r++) {
                    float v = fmaxf(acc1[rt][ct][r] + b2v[ct], 0.f);
                    m1_lds[(rt * 16 + q * 4 + r) * 136 + col] = f2bf(v);
                }
            }
        }
        __syncthreads();

        // GEMM2: m2 = relu(m1 @ W3 + b3), K=128
        f32x4 acc2[4][2];
        #pragma unroll
        for (int rt = 0; rt < 4; rt++)
            #pragma unroll
            for (int ct = 0; ct < 2; ct++) acc2[rt][ct] = (f32x4){0.f, 0.f, 0.f, 0.f};
        #pragma unroll
        for (int kt = 0; kt < 4; kt++) {
            #pragma unroll
            for (int rt = 0; rt < 4; rt++) {
                bf16x8 a = __builtin_bit_cast(bf16x8,
                    *(const u32x4*)(&m1_lds[(rt * 16 + lr) * 136 + kt * 32 + q * 8]));
                acc2[rt][0] = __builtin_amdgcn_mfma_f32_16x16x32_bf16(a, b3f[0][kt], acc2[rt][0], 0, 0, 0);
                acc2[rt][1] = __builtin_amdgcn_mfma_f32_16x16x32_bf16(a, b3f[1][kt], acc2[rt][1], 0, 0, 0);
            }
        }
        // write fp32 m2 into reused e_lds ([64][132]: bank = 4*row+col mod 32, 2-way max)
        #pragma unroll
        for (int rt = 0; rt < 4; rt++) {
            #pragma unroll
            for (int ct = 0; ct < 2; ct++) {
                int col = (2 * w + ct) * 16 + lr;
                #pragma unroll
                for (int r = 0; r < 4; r++) {
                    float v = fmaxf(acc2[rt][ct][r] + b3v[ct], 0.f);
                    m2f[(rt * 16 + q * 4 + r) * 132 + col] = v;
                }
            }
        }
        __syncthreads();

        // segmented max over sorted dst runs: thread -> (col = tid&127, rows r0..r0+31)
        {
            int col = tid & 127;
            int r0 = (tid >> 7) * 32;
            float cur = m2f[r0 * 132 + col];
            int d = s_dst[r0];                          // wave-uniform
            #pragma unroll 4
            for (int i = 1; i < 32; i++) {
                int dn = s_dst[r0 + i];                 // wave-uniform
                float v = m2f[(r0 + i) * 132 + col];
                if (dn != d) {                          // wave-uniform branch
                    atomicMax(&out[(size_t)d * DIM + col], __float_as_uint(cur));
                    d = dn; cur = v;
                } else {
                    cur = fmaxf(cur, v);
                }
            }
            atomicMax(&out[(size_t)d * DIM + col], __float_as_uint(cur));
        }
        __syncthreads();   // protect s_dst/e_lds/m1_lds before next tile
    }
}

extern "C" void kernel_launch(void* const* d_in, const int* in_sizes, int n_in,
                              void* d_out, int out_size, void* d_ws, size_t ws_size,
                              hipStream_t stream) {
    const float* x  = (const float*)d_in[0];
    const int* eidx = (const int*)d_in[1];
    const float* W1 = (const float*)d_in[2];
    const float* b1 = (const float*)d_in[3];
    const float* W2 = (const float*)d_in[4];
    const float* b2 = (const float*)d_in[5];
    const float* W3 = (const float*)d_in[6];
    const float* b3 = (const float*)d_in[7];

    char* ws = (char*)d_ws;
    unsigned short* hbf = (unsigned short*)ws;                     // 12,800,000 B
    unsigned short* W2t = (unsigned short*)(ws + 12800000);        // 65,536 B
    unsigned short* W3t = (unsigned short*)(ws + 12865536);        // 32,768 B
    int* cnt            = (int*)(ws + 12898304);                   // 200,000 B (counts -> cursor)
    int* ssrc           = (int*)(ws + 13098496);                   // 3,200,000 B
    int* sdst           = (int*)(ws + 16298496);                   // 3,200,000 B -> 19,498,496 total

    hipMemsetAsync(d_out, 0, (size_t)N_NODES * DIM * sizeof(float), stream);
    hipMemsetAsync(cnt, 0, N_NODES * sizeof(int), stream);
    convert_w_kernel<<<192, 256, 0, stream>>>(W2, W3, W2t, W3t);
    hist_kernel<<<(N_EDGES + 255) / 256, 256, 0, stream>>>(eidx, cnt);
    lin1_kernel<<<(N_NODES + 63) / 64, 256, 0, stream>>>(x, W1, b1, hbf);
    scan_kernel<<<1, 1024, 0, stream>>>(cnt);
    scatter_kernel<<<(N_EDGES + 255) / 256, 256, 0, stream>>>(eidx, cnt, ssrc, sdst);
    edge_kernel<<<2048, 256, 0, stream>>>(hbf, ssrc, sdst, W2t, W3t, b2, b3, (unsigned int*)d_out);
}

// Round 3
// 351.565 us; speedup vs baseline: 1.2993x; 1.2993x over previous
//
#include <hip/hip_runtime.h>
#include <hip/hip_bf16.h>

#define N_NODES 50000
#define N_EDGES 800000
#define DIM 128
#define NTILES (N_EDGES / 64)   // 12500 exactly
#define SCAN_B 196              // ceil(50000/256)

typedef __bf16 bf16x8 __attribute__((ext_vector_type(8)));
typedef float f32x4 __attribute__((ext_vector_type(4)));
typedef unsigned int u32x4 __attribute__((ext_vector_type(4)));

__device__ __forceinline__ unsigned short f2bf(float f) {
    unsigned u = __float_as_uint(f);
    u += 0x7fffu + ((u >> 16) & 1u);          // round-to-nearest-even
    return (unsigned short)(u >> 16);
}

// ---- weights: Wat[n][k]=bf16(W2a-W2b)^T, Wbt[n][k]=bf16(W2b)^T, W3t[n][k]=bf16(W3)^T
// identity: [h_i, h_j-h_i] @ W2 = h_i @ (W2a - W2b) + h_j @ W2b   (removes per-edge subtract VALU)
__global__ void convert_w_kernel(const float* __restrict__ W2, const float* __restrict__ W3,
                                 unsigned short* __restrict__ Wat, unsigned short* __restrict__ Wbt,
                                 unsigned short* __restrict__ W3t) {
    int i = blockIdx.x * 256 + threadIdx.x;   // grid covers exactly 3*16384 = 49152
    if (i < DIM * DIM) {
        int k = i >> 7, n = i & 127;
        Wat[n * 128 + k] = f2bf(W2[k * 128 + n] - W2[(k + 128) * 128 + n]);
    } else if (i < 2 * DIM * DIM) {
        int j = i - DIM * DIM;
        int k = j >> 7, n = j & 127;
        Wbt[n * 128 + k] = f2bf(W2[(k + 128) * 128 + n]);
    } else {
        int j = i - 2 * DIM * DIM;
        int k = j >> 7, n = j & 127;
        W3t[n * 128 + k] = f2bf(W3[k * 128 + n]);
    }
}

// ---- counting sort by dst: histogram
__global__ void hist_kernel(const int* __restrict__ eidx, int* __restrict__ cnt) {
    int e = blockIdx.x * 256 + threadIdx.x;
    if (e < N_EDGES) atomicAdd(&cnt[eidx[N_EDGES + e]], 1);
}

// ---- hierarchical exclusive scan of cnt[N_NODES]: A (per-block) -> B (block totals) -> C (add offsets)
__global__ void scanA_kernel(int* __restrict__ cnt, int* __restrict__ aux) {
    __shared__ int buf[256];
    int t = threadIdx.x, i = blockIdx.x * 256 + t;
    int v = (i < N_NODES) ? cnt[i] : 0;
    buf[t] = v;
    __syncthreads();
    for (int off = 1; off < 256; off <<= 1) {
        int u = (t >= off) ? buf[t - off] : 0;
        __syncthreads();
        buf[t] += u;
        __syncthreads();
    }
    if (i < N_NODES) cnt[i] = buf[t] - v;         // exclusive within block
    if (t == 255) aux[blockIdx.x] = buf[255];     // block total
}

__global__ void scanB_kernel(int* __restrict__ aux) {
    __shared__ int buf[256];
    int t = threadIdx.x;
    int v = (t < SCAN_B) ? aux[t] : 0;
    buf[t] = v;
    __syncthreads();
    for (int off = 1; off < 256; off <<= 1) {
        int u = (t >= off) ? buf[t - off] : 0;
        __syncthreads();
        buf[t] += u;
        __syncthreads();
    }
    if (t < SCAN_B) aux[t] = buf[t] - v;          // exclusive block offsets
}

__global__ void scanC_kernel(int* __restrict__ cnt, const int* __restrict__ aux) {
    int i = blockIdx.x * 256 + threadIdx.x;
    if (i < N_NODES) cnt[i] += aux[blockIdx.x];
}

// ---- scatter edges into dst-sorted order, packed (src,dst) int2: one 8B write/edge
__global__ void scatter_kernel(const int* __restrict__ eidx, int* __restrict__ cursor,
                               int2* __restrict__ spair) {
    int e = blockIdx.x * 256 + threadIdx.x;
    if (e < N_EDGES) {
        int d = eidx[N_EDGES + e];
        int p = atomicAdd(&cursor[d], 1);
        spair[p] = make_int2(eidx[e], d);
    }
}

// ---- lin1: hbf[N][128] = bf16(x @ W1 + b1), MFMA 16x16x32, W1 transposed in LDS
__global__ __launch_bounds__(256, 2) void lin1_kernel(const float* __restrict__ x,
        const float* __restrict__ W1, const float* __restrict__ b1,
        unsigned short* __restrict__ hbf) {
    __shared__ __align__(16) unsigned short w1t[128 * 136];
    int tid = threadIdx.x;
    for (int i = tid; i < DIM * DIM; i += 256) {
        int k = i >> 7, n = i & 127;
        w1t[n * 136 + k] = f2bf(W1[i]);
    }
    __syncthreads();
    int w = tid >> 6, lane = tid & 63;
    int lr = lane & 15, q = lane >> 4;
    int row0 = blockIdx.x * 64 + w * 16;
    int rowA = row0 + lr; if (rowA >= N_NODES) rowA = N_NODES - 1;
    f32x4 acc[8];
    #pragma unroll
    for (int ct = 0; ct < 8; ct++) acc[ct] = (f32x4){0.f, 0.f, 0.f, 0.f};
    #pragma unroll
    for (int kt = 0; kt < 4; kt++) {
        const float* ap = x + (size_t)rowA * DIM + kt * 32 + q * 8;
        bf16x8 a;
        #pragma unroll
        for (int j = 0; j < 8; j++) a[j] = (__bf16)ap[j];
        #pragma unroll
        for (int ct = 0; ct < 8; ct++) {
            bf16x8 b = __builtin_bit_cast(bf16x8,
                *(const u32x4*)(&w1t[(ct * 16 + lr) * 136 + kt * 32 + q * 8]));
            acc[ct] = __builtin_amdgcn_mfma_f32_16x16x32_bf16(a, b, acc[ct], 0, 0, 0);
        }
    }
    #pragma unroll
    for (int ct = 0; ct < 8; ct++) {
        int col = ct * 16 + lr;
        float bias = b1[col];
        #pragma unroll
        for (int r = 0; r < 4; r++) {
            int row = row0 + q * 4 + r;   // C/D: col=lane&15, row=quad*4+reg
            if (row < N_NODES)
                hbf[(size_t)row * DIM + col] = f2bf(acc[ct][r] + bias);
        }
    }
}

// ---- fused edge MLP + segmented scatter-max over dst-sorted edges
__global__ __launch_bounds__(256, 2) void edge_kernel(
        const unsigned short* __restrict__ hbf,
        const int2* __restrict__ spair,
        const unsigned short* __restrict__ Wat,
        const unsigned short* __restrict__ Wbt,
        const unsigned short* __restrict__ W3t,
        const float* __restrict__ b2,
        const float* __restrict__ b3,
        unsigned int* __restrict__ out) {
    __shared__ __align__(16) unsigned short gbuf[2 * 64 * 136];  // hi|hj tiles; reused as fp32 m2 [64][132]
    __shared__ __align__(16) unsigned short m1_lds[64 * 136];
    __shared__ int s_src[64];
    __shared__ int s_dst[64];

    unsigned short* hi_lds = gbuf;
    unsigned short* hj_lds = gbuf + 64 * 136;
    float* m2f = (float*)gbuf;                                   // [64][132] fp32

    int tid = threadIdx.x;
    int w = tid >> 6, lane = tid & 63;
    int lr = lane & 15, q = lane >> 4;

    // register-cached B fragments (fixed cols per wave, amortized over grid-stride loop)
    bf16x8 baf[2][4], bbf[2][4], b3f[2][4];
    float b2v[2], b3v[2];
    #pragma unroll
    for (int ct = 0; ct < 2; ct++) {
        int n = (2 * w + ct) * 16 + lr;
        #pragma unroll
        for (int kt = 0; kt < 4; kt++) {
            baf[ct][kt] = __builtin_bit_cast(bf16x8, *(const u32x4*)(&Wat[n * 128 + kt * 32 + q * 8]));
            bbf[ct][kt] = __builtin_bit_cast(bf16x8, *(const u32x4*)(&Wbt[n * 128 + kt * 32 + q * 8]));
            b3f[ct][kt] = __builtin_bit_cast(bf16x8, *(const u32x4*)(&W3t[n * 128 + kt * 32 + q * 8]));
        }
        b2v[ct] = b2[n];
        b3v[ct] = b3[n];
    }

    for (int tb = blockIdx.x; tb < NTILES; tb += gridDim.x) {
        int eb = tb * 64;
        if (tid < 64) {
            int2 v = spair[eb + tid];
            s_src[tid] = v.x;
            s_dst[tid] = v.y;
        }
        __syncthreads();

        // gather: pure 16B copies (no per-edge arithmetic)
        #pragma unroll
        for (int it = 0; it < 4; it++) {
            int i = tid + it * 256;
            int t = i >> 4, c = (i & 15) * 8;
            *(u32x4*)(&hi_lds[t * 136 + c]) = *(const u32x4*)(&hbf[(size_t)s_dst[t] * DIM + c]);
            *(u32x4*)(&hj_lds[t * 136 + c]) = *(const u32x4*)(&hbf[(size_t)s_src[t] * DIM + c]);
        }
        __syncthreads();

        // GEMM1: m1 = relu(h_i@Wa + h_j@Wb + b2), two K=128 passes
        f32x4 acc1[4][2];
        #pragma unroll
        for (int rt = 0; rt < 4; rt++)
            #pragma unroll
            for (int ct = 0; ct < 2; ct++) acc1[rt][ct] = (f32x4){0.f, 0.f, 0.f, 0.f};
        #pragma unroll
        for (int kt = 0; kt < 4; kt++) {
            #pragma unroll
            for (int rt = 0; rt < 4; rt++) {
                bf16x8 ai = __builtin_bit_cast(bf16x8,
                    *(const u32x4*)(&hi_lds[(rt * 16 + lr) * 136 + kt * 32 + q * 8]));
                bf16x8 aj = __builtin_bit_cast(bf16x8,
                    *(const u32x4*)(&hj_lds[(rt * 16 + lr) * 136 + kt * 32 + q * 8]));
                acc1[rt][0] = __builtin_amdgcn_mfma_f32_16x16x32_bf16(ai, baf[0][kt], acc1[rt][0], 0, 0, 0);
                acc1[rt][1] = __builtin_amdgcn_mfma_f32_16x16x32_bf16(ai, baf[1][kt], acc1[rt][1], 0, 0, 0);
                acc1[rt][0] = __builtin_amdgcn_mfma_f32_16x16x32_bf16(aj, bbf[0][kt], acc1[rt][0], 0, 0, 0);
                acc1[rt][1] = __builtin_amdgcn_mfma_f32_16x16x32_bf16(aj, bbf[1][kt], acc1[rt][1], 0, 0, 0);
            }
        }
        #pragma unroll
        for (int rt = 0; rt < 4; rt++) {
            #pragma unroll
            for (int ct = 0; ct < 2; ct++) {
                int col = (2 * w + ct) * 16 + lr;
                #pragma unroll
                for (int r = 0; r < 4; r++) {
                    float v = fmaxf(acc1[rt][ct][r] + b2v[ct], 0.f);
                    m1_lds[(rt * 16 + q * 4 + r) * 136 + col] = f2bf(v);
                }
            }
        }
        __syncthreads();   // m1 ready; also: all GEMM1 reads of hi/hj done -> m2f reuse safe

        // GEMM2: m2 = relu(m1 @ W3 + b3), K=128
        f32x4 acc2[4][2];
        #pragma unroll
        for (int rt = 0; rt < 4; rt++)
            #pragma unroll
            for (int ct = 0; ct < 2; ct++) acc2[rt][ct] = (f32x4){0.f, 0.f, 0.f, 0.f};
        #pragma unroll
        for (int kt = 0; kt < 4; kt++) {
            #pragma unroll
            for (int rt = 0; rt < 4; rt++) {
                bf16x8 a = __builtin_bit_cast(bf16x8,
                    *(const u32x4*)(&m1_lds[(rt * 16 + lr) * 136 + kt * 32 + q * 8]));
                acc2[rt][0] = __builtin_amdgcn_mfma_f32_16x16x32_bf16(a, b3f[0][kt], acc2[rt][0], 0, 0, 0);
                acc2[rt][1] = __builtin_amdgcn_mfma_f32_16x16x32_bf16(a, b3f[1][kt], acc2[rt][1], 0, 0, 0);
            }
        }
        #pragma unroll
        for (int rt = 0; rt < 4; rt++) {
            #pragma unroll
            for (int ct = 0; ct < 2; ct++) {
                int col = (2 * w + ct) * 16 + lr;
                #pragma unroll
                for (int r = 0; r < 4; r++) {
                    float v = fmaxf(acc2[rt][ct][r] + b3v[ct], 0.f);
                    m2f[(rt * 16 + q * 4 + r) * 132 + col] = v;
                }
            }
        }
        __syncthreads();

        // segmented max over sorted dst runs: thread -> (col = tid&127, rows r0..r0+31)
        {
            int col = tid & 127;
            int r0 = (tid >> 7) * 32;
            float cur = m2f[r0 * 132 + col];
            int d = s_dst[r0];                          // wave-uniform
            #pragma unroll 4
            for (int i = 1; i < 32; i++) {
                int dn = s_dst[r0 + i];                 // wave-uniform
                float v = m2f[(r0 + i) * 132 + col];
                if (dn != d) {                          // wave-uniform branch
                    atomicMax(&out[(size_t)d * DIM + col], __float_as_uint(cur));
                    d = dn; cur = v;
                } else {
                    cur = fmaxf(cur, v);
                }
            }
            atomicMax(&out[(size_t)d * DIM + col], __float_as_uint(cur));
        }
        __syncthreads();   // protect s_dst/gbuf/m1_lds before next tile
    }
}

extern "C" void kernel_launch(void* const* d_in, const int* in_sizes, int n_in,
                              void* d_out, int out_size, void* d_ws, size_t ws_size,
                              hipStream_t stream) {
    const float* x  = (const float*)d_in[0];
    const int* eidx = (const int*)d_in[1];
    const float* W1 = (const float*)d_in[2];
    const float* b1 = (const float*)d_in[3];
    const float* W2 = (const float*)d_in[4];
    const float* b2 = (const float*)d_in[5];
    const float* W3 = (const float*)d_in[6];
    const float* b3 = (const float*)d_in[7];

    char* ws = (char*)d_ws;
    unsigned short* hbf = (unsigned short*)ws;                     // 12,800,000 B
    unsigned short* Wat = (unsigned short*)(ws + 12800000);        // 32,768 B
    unsigned short* Wbt = (unsigned short*)(ws + 12832768);        // 32,768 B
    unsigned short* W3t = (unsigned short*)(ws + 12865536);        // 32,768 B
    int* cnt            = (int*)(ws + 12898304);                   // 200,000 B (counts -> cursor)
    int2* spair         = (int2*)(ws + 13098496);                  // 6,400,000 B -> 19,498,496 total
    int* aux            = (int*)spair;                             // aliases spair: dead before scatter writes

    hipMemsetAsync(d_out, 0, (size_t)N_NODES * DIM * sizeof(float), stream);
    hipMemsetAsync(cnt, 0, N_NODES * sizeof(int), stream);
    convert_w_kernel<<<192, 256, 0, stream>>>(W2, W3, Wat, Wbt, W3t);
    hist_kernel<<<(N_EDGES + 255) / 256, 256, 0, stream>>>(eidx, cnt);
    lin1_kernel<<<(N_NODES + 63) / 64, 256, 0, stream>>>(x, W1, b1, hbf);
    scanA_kernel<<<SCAN_B, 256, 0, stream>>>(cnt, aux);
    scanB_kernel<<<1, 256, 0, stream>>>(aux);
    scanC_kernel<<<SCAN_B, 256, 0, stream>>>(cnt, aux);
    scatter_kernel<<<(N_EDGES + 255) / 256, 256, 0, stream>>>(eidx, cnt, spair);
    edge_kernel<<<2048, 256, 0, stream>>>(hbf, spair, Wat, Wbt, W3t, b2, b3, (unsigned int*)d_out);
}